// Round 1
// baseline (672.771 us; speedup 1.0000x reference)
//
#include <hip/hip_runtime.h>

// ---------------------------------------------------------------------------
// VanillaSFNN: x[256,1000,700] -> currents GEMM -> LIF spikes -> readout leaky
// integrator + softmax accumulation.
//
// Pipeline:
//   k0 wprep   : W_h f32 -> split bf16 hi/lo packed in MFMA fragment order
//   k1 gemm    : currents[r=b*1000+t][h] via 3-term split-bf16 MFMA
//   k2 lif     : per-batch wave, lane=neuron, spikes -> 64-bit ballot masks
//   k3 rin     : R'[t][b][o] = (1-beta_o) * (b_r[o] + sum_h s*W_r[o][h])
//   k4 scanE   : per T-chunk end-state of linear v_ro recurrence (no init)
//   k5 carry   : sequential chunk-carry combine per (b,o)
//   k6 scanSoft: per-chunk v_ro scan + softmax accumulation (t>10 mask)
//   k7 reduce  : sum chunk partials -> d_out[b][o]
// ---------------------------------------------------------------------------

typedef float  f32x4  __attribute__((ext_vector_type(4)));
typedef short  short8 __attribute__((ext_vector_type(8)));
typedef unsigned long long ull;

#define B_   256
#define T_   1000
#define K_   700
#define H_   64
#define O_   20
#define M_   256000      // B*T
#define NKT  11          // ceil(700/64)
#define TC   40          // T-chunk length
#define NC   25          // number of chunks

// workspace layout (bytes)
#define OFF_WFRAG  ((size_t)0)            // 11*16384 = 180,224
#define OFF_CUR    ((size_t)262144)       // 256000*64*4 = 65,536,000
#define OFF_MASK   ((size_t)65798144)     // 256000*8    =  2,048,000
#define OFF_R      ((size_t)67846144)     // 1000*256*20*4 = 20,480,000
#define OFF_E      ((size_t)88326144)     // 25*5120*4 = 512,000
#define OFF_S      ((size_t)88838144)     // 512,000
#define OFF_PACC   ((size_t)89350144)     // 512,000

// ---------------------------------------------------------------------------
// k0: pack W_h into fragment-ordered split-bf16.
// Per k-tile kt (64 k's): hi region 8192B then lo region 8192B.
// Slot s = (nf*2+kf)*64 + lane holds 8 bf16: h = nf*16+(lane&15),
// k = kt*64 + kf*32 + ((lane>>4)&3)*8 + j.
// ---------------------------------------------------------------------------
__global__ void wprep(const float* __restrict__ Wh, unsigned short* __restrict__ wfrag) {
    int e = blockIdx.x * 256 + threadIdx.x;          // 22*256 = 5632 exact
    int kt   = e >> 9;
    int rem  = e & 511;
    int nf   = rem >> 7;
    int kf   = (rem >> 6) & 1;
    int lane = rem & 63;
    int h     = nf * 16 + (lane & 15);
    int kbase = kt * 64 + kf * 32 + ((lane >> 4) & 3) * 8;
    int slot  = (nf * 2 + kf) * 64 + lane;
    unsigned short* dh = wfrag + (size_t)kt * 8192 + slot * 8;
    unsigned short* dl = dh + 4096;
#pragma unroll
    for (int j = 0; j < 8; ++j) {
        int k = kbase + j;
        float v = (k < K_) ? Wh[(size_t)h * K_ + k] : 0.0f;
        unsigned u  = __builtin_bit_cast(unsigned, v);
        float    fh = __builtin_bit_cast(float, u & 0xffff0000u);
        float    r  = v - fh;
        dh[j] = (unsigned short)(u >> 16);
        dl[j] = (unsigned short)(__builtin_bit_cast(unsigned, r) >> 16);
    }
}

// ---------------------------------------------------------------------------
// k1: GEMM  currents[r][h] = sum_k x[r][k]*W_h[h][k] + b_h[h]
// 128-row tile, 4 waves; wave owns 2 m-frags; W staged to LDS (frag order),
// x loaded global->reg and chop-split to bf16 hi/lo in registers.
// ---------------------------------------------------------------------------
__device__ __forceinline__ void splitpair(f32x4 p0, f32x4 p1, short8& hi, short8& lo) {
#pragma unroll
    for (int j = 0; j < 4; ++j) {
        {
            unsigned u  = __builtin_bit_cast(unsigned, p0[j]);
            float    fh = __builtin_bit_cast(float, u & 0xffff0000u);
            float    r  = p0[j] - fh;
            hi[j] = (short)(u >> 16);
            lo[j] = (short)(__builtin_bit_cast(unsigned, r) >> 16);
        }
        {
            unsigned u  = __builtin_bit_cast(unsigned, p1[j]);
            float    fh = __builtin_bit_cast(float, u & 0xffff0000u);
            float    r  = p1[j] - fh;
            hi[j + 4] = (short)(u >> 16);
            lo[j + 4] = (short)(__builtin_bit_cast(unsigned, r) >> 16);
        }
    }
}

template <bool GUARD>
__device__ __forceinline__ void gemm_kstep(int kt, int tid, int lane, int klane,
                                           const float* xA0, const float* xA1,
                                           const unsigned short* __restrict__ wfrag,
                                           uint4* sWbuf, f32x4 (&acc)[2][4]) {
    // stage W tile (16 KB) -- linear, conflict-free
    const uint4* wsrc = (const uint4*)(wfrag + (size_t)kt * 8192);
#pragma unroll
    for (int j = 0; j < 4; ++j) sWbuf[j * 256 + tid] = wsrc[j * 256 + tid];
    __syncthreads();

    const short8* sWh8 = (const short8*)sWbuf;
    const short8* sWl8 = (const short8*)((const char*)sWbuf + 8192);
    const float* xA[2] = {xA0, xA1};

#pragma unroll
    for (int kf = 0; kf < 2; ++kf) {
        int k0 = kt * 64 + kf * 32 + klane;
        short8 ah[2], al[2];
#pragma unroll
        for (int i = 0; i < 2; ++i) {
            f32x4 p0 = *(const f32x4*)(xA[i] + k0);
            f32x4 p1 = {0.f, 0.f, 0.f, 0.f};
            if (!GUARD || (k0 + 4 < K_)) p1 = *(const f32x4*)(xA[i] + k0 + 4);
            splitpair(p0, p1, ah[i], al[i]);
        }
#pragma unroll
        for (int n = 0; n < 4; ++n) {
            short8 bhf = sWh8[(n * 2 + kf) * 64 + lane];
            short8 blf = sWl8[(n * 2 + kf) * 64 + lane];
#pragma unroll
            for (int i = 0; i < 2; ++i) {
                acc[i][n] = __builtin_amdgcn_mfma_f32_16x16x32_bf16(ah[i], bhf, acc[i][n], 0, 0, 0);
                acc[i][n] = __builtin_amdgcn_mfma_f32_16x16x32_bf16(al[i], bhf, acc[i][n], 0, 0, 0);
                acc[i][n] = __builtin_amdgcn_mfma_f32_16x16x32_bf16(ah[i], blf, acc[i][n], 0, 0, 0);
            }
        }
    }
    __syncthreads();
}

__global__ __launch_bounds__(256) void gemm_cur(const float* __restrict__ x,
                                                const unsigned short* __restrict__ wfrag,
                                                const float* __restrict__ b_h,
                                                float* __restrict__ cur) {
    __shared__ uint4 sWbuf[1024];   // 16 KB: hi 8 KB + lo 8 KB
    int tid  = threadIdx.x;
    int lane = tid & 63;
    int wid  = tid >> 6;
    int row0 = blockIdx.x * 128;
    int klane = ((lane >> 4) & 3) * 8;

    const float* xA0 = x + (size_t)(row0 + (wid * 2 + 0) * 16 + (lane & 15)) * K_;
    const float* xA1 = x + (size_t)(row0 + (wid * 2 + 1) * 16 + (lane & 15)) * K_;

    float bh4[4];
#pragma unroll
    for (int n = 0; n < 4; ++n) bh4[n] = b_h[n * 16 + (lane & 15)];

    f32x4 acc[2][4];
#pragma unroll
    for (int i = 0; i < 2; ++i)
#pragma unroll
        for (int n = 0; n < 4; ++n) acc[i][n] = (f32x4){0.f, 0.f, 0.f, 0.f};

    for (int kt = 0; kt < 10; ++kt)
        gemm_kstep<false>(kt, tid, lane, klane, xA0, xA1, wfrag, sWbuf, acc);
    gemm_kstep<true>(10, tid, lane, klane, xA0, xA1, wfrag, sWbuf, acc);

    // epilogue: C/D layout col = lane&15, row = (lane>>4)*4 + j
#pragma unroll
    for (int i = 0; i < 2; ++i) {
        int row = row0 + (wid * 2 + i) * 16 + ((lane >> 4) & 3) * 4;
#pragma unroll
        for (int n = 0; n < 4; ++n) {
#pragma unroll
            for (int j = 0; j < 4; ++j) {
                cur[(size_t)(row + j) * H_ + n * 16 + (lane & 15)] = acc[i][n][j] + bh4[n];
            }
        }
    }
}

// ---------------------------------------------------------------------------
// k2: LIF. One wave per batch, lane = neuron. v=(v+cur)/2; spike v>=1; reset.
// ---------------------------------------------------------------------------
__global__ void lif(const float* __restrict__ cur, ull* __restrict__ masks) {
    int b = blockIdx.x;
    int h = threadIdx.x;
    const float* p = cur + (size_t)b * T_ * H_ + h;
    ull* mp = masks + (size_t)b * T_;
    float v = 0.0f;
#pragma unroll 4
    for (int t = 0; t < T_; ++t) {
        float c = p[(size_t)t * H_];
        v = (v + c) * 0.5f;
        bool s = (v >= 1.0f);
        ull m = __ballot(s);
        if (h == 0) mp[t] = m;
        v = s ? 0.0f : v;
    }
}

// ---------------------------------------------------------------------------
// k3: R'[t][b][o] = (1-beta_o)*(b_r[o] + sum_h s[h]*W_r[o][h])
// ---------------------------------------------------------------------------
__global__ void rin(const ull* __restrict__ masks, const float* __restrict__ Wr,
                    const float* __restrict__ br, const float* __restrict__ tau,
                    float* __restrict__ R) {
    __shared__ float sw[20 * 65];   // padded: bank = (o+h)%32, conflict-free
    int tid = threadIdx.x;
    for (int i = tid; i < 1280; i += 256) sw[(i >> 6) * 65 + (i & 63)] = Wr[i];
    __syncthreads();

    int g  = blockIdx.x * 256 + tid;     // < 5,120,000 exact
    int o  = g % 20;
    int tb = g / 20;
    int b  = tb & 255;
    int t  = tb >> 8;
    ull m = masks[(size_t)b * T_ + t];
    unsigned mlo = (unsigned)m, mhi = (unsigned)(m >> 32);
    const float* w = &sw[o * 65];
    float sum = br[o];
#pragma unroll
    for (int hh = 0; hh < 32; ++hh) sum += ((mlo >> hh) & 1u) ? w[hh] : 0.0f;
#pragma unroll
    for (int hh = 0; hh < 32; ++hh) sum += ((mhi >> hh) & 1u) ? w[32 + hh] : 0.0f;
    float beta = 1.0f / (1.0f + __expf(-tau[o]));
    R[g] = (1.0f - beta) * sum;
}

// ---------------------------------------------------------------------------
// k4: per-chunk end state (zero init):  E_c = sum_{j} beta^{TC-1-j} R'[t0+j]
// ---------------------------------------------------------------------------
__global__ void scanE(const float* __restrict__ R, const float* __restrict__ tau,
                      float* __restrict__ E) {
    int c = blockIdx.x >> 2;
    int b = ((blockIdx.x & 3) << 6) | threadIdx.x;
    float beta[20], v[20];
#pragma unroll
    for (int o = 0; o < 20; ++o) { beta[o] = 1.0f / (1.0f + __expf(-tau[o])); v[o] = 0.0f; }
    int t0 = c * TC;
    for (int j = 0; j < TC; ++j) {
        const f32x4* p = (const f32x4*)(R + (size_t)(t0 + j) * 5120 + b * 20);
        f32x4 q[5];
#pragma unroll
        for (int i = 0; i < 5; ++i) q[i] = p[i];
#pragma unroll
        for (int o = 0; o < 20; ++o) v[o] = beta[o] * v[o] + q[o >> 2][o & 3];
    }
    float* e = E + ((size_t)c * 256 + b) * 20;
#pragma unroll
    for (int o = 0; o < 20; ++o) e[o] = v[o];
}

// ---------------------------------------------------------------------------
// k5: carry combine: S_c = beta^TC * S_{c-1} + E_{c-1}, S_0 = 0
// ---------------------------------------------------------------------------
__global__ void carry(const float* __restrict__ E, const float* __restrict__ tau,
                      float* __restrict__ S) {
    int g = blockIdx.x * 256 + threadIdx.x;   // 5120 exact
    int o = g % 20;
    float beta = 1.0f / (1.0f + __expf(-tau[o]));
    float bp = exp2f((float)TC * log2f(beta));
    float s = 0.0f;
    for (int c = 0; c < NC; ++c) {
        S[(size_t)c * 5120 + g] = s;
        s = bp * s + E[(size_t)c * 5120 + g];
    }
}

// ---------------------------------------------------------------------------
// k6: per-chunk scan with softmax accumulation (mask t>10)
// ---------------------------------------------------------------------------
__global__ void scanSoft(const float* __restrict__ R, const float* __restrict__ S,
                         const float* __restrict__ tau, float* __restrict__ pacc) {
    int c = blockIdx.x >> 2;
    int b = ((blockIdx.x & 3) << 6) | threadIdx.x;
    size_t sb = ((size_t)c * 256 + b) * 20;
    float beta[20], v[20], acc[20];
#pragma unroll
    for (int o = 0; o < 20; ++o) {
        beta[o] = 1.0f / (1.0f + __expf(-tau[o]));
        v[o] = S[sb + o];
        acc[o] = 0.0f;
    }
    int t0 = c * TC;
    for (int j = 0; j < TC; ++j) {
        int t = t0 + j;
        const f32x4* p = (const f32x4*)(R + (size_t)t * 5120 + b * 20);
        f32x4 q[5];
#pragma unroll
        for (int i = 0; i < 5; ++i) q[i] = p[i];
#pragma unroll
        for (int o = 0; o < 20; ++o) v[o] = beta[o] * v[o] + q[o >> 2][o & 3];
        if (t >= 11) {
            float mx = v[0];
#pragma unroll
            for (int o = 1; o < 20; ++o) mx = fmaxf(mx, v[o]);
            float e[20], ssum = 0.0f;
#pragma unroll
            for (int o = 0; o < 20; ++o) { e[o] = __expf(v[o] - mx); ssum += e[o]; }
            float inv = 1.0f / ssum;
#pragma unroll
            for (int o = 0; o < 20; ++o) acc[o] += e[o] * inv;
        }
    }
#pragma unroll
    for (int o = 0; o < 20; ++o) pacc[sb + o] = acc[o];
}

// ---------------------------------------------------------------------------
// k7: reduce chunk partials
// ---------------------------------------------------------------------------
__global__ void reduceAcc(const float* __restrict__ pacc, float* __restrict__ out) {
    int g = blockIdx.x * 256 + threadIdx.x;   // 5120 exact
    float s = 0.0f;
    for (int c = 0; c < NC; ++c) s += pacc[(size_t)c * 5120 + g];
    out[g] = s;
}

// ---------------------------------------------------------------------------
extern "C" void kernel_launch(void* const* d_in, const int* in_sizes, int n_in,
                              void* d_out, int out_size, void* d_ws, size_t ws_size,
                              hipStream_t stream) {
    const float* x   = (const float*)d_in[0];
    const float* W_h = (const float*)d_in[1];
    const float* b_h = (const float*)d_in[2];
    const float* W_r = (const float*)d_in[3];
    const float* b_r = (const float*)d_in[4];
    const float* tau = (const float*)d_in[5];

    char* ws = (char*)d_ws;
    unsigned short* wfrag = (unsigned short*)(ws + OFF_WFRAG);
    float* cur  = (float*)(ws + OFF_CUR);
    ull*   msk  = (ull*)(ws + OFF_MASK);
    float* R    = (float*)(ws + OFF_R);
    float* E    = (float*)(ws + OFF_E);
    float* S    = (float*)(ws + OFF_S);
    float* pacc = (float*)(ws + OFF_PACC);
    float* out  = (float*)d_out;

    wprep<<<22, 256, 0, stream>>>(W_h, wfrag);
    gemm_cur<<<2000, 256, 0, stream>>>(x, wfrag, b_h, cur);
    lif<<<256, 64, 0, stream>>>(cur, msk);
    rin<<<20000, 256, 0, stream>>>(msk, W_r, b_r, tau, R);
    scanE<<<100, 64, 0, stream>>>(R, tau, E);
    carry<<<20, 256, 0, stream>>>(E, tau, S);
    scanSoft<<<100, 64, 0, stream>>>(R, S, tau, pacc);
    reduceAcc<<<20, 256, 0, stream>>>(pacc, out);
}

// Round 2
// 344.533 us; speedup vs baseline: 1.9527x; 1.9527x over previous
//
#include <hip/hip_runtime.h>

// ---------------------------------------------------------------------------
// VanillaSFNN: x[256,1000,700] -> currents GEMM -> LIF spikes -> readout leaky
// integrator + softmax accumulation.
//
// Pipeline:
//   k0 wprep   : W_h f32 -> split bf16 hi/lo packed in MFMA fragment order
//   k1 gemm    : currents[r=b*1000+t][h] via 3-term split-bf16 MFMA (no LDS)
//   k2 lif     : chunked speculative scan (burn-in 40), spikes -> ballot masks
//   k3 rin     : R'[t][b][o] via set-bit iteration over W_r^T in LDS
//   k4 scanE   : per T-chunk end-state of linear v_ro recurrence (no init)
//   k5 carry   : sequential chunk-carry combine per (b,o)
//   k6 scanSoft: per-chunk v_ro scan + softmax accumulation (t>10 mask)
//   k7 reduce  : sum chunk partials -> d_out[b][o]
// ---------------------------------------------------------------------------

typedef float  f32x4  __attribute__((ext_vector_type(4)));
typedef short  short8 __attribute__((ext_vector_type(8)));
typedef unsigned long long ull;

#define B_   256
#define T_   1000
#define K_   700
#define H_   64
#define O_   20
#define M_   256000      // B*T
#define TC   20          // v_ro scan chunk length
#define NC   50          // number of v_ro chunks
#define TCL  100         // LIF chunk length
#define NCL  10          // LIF chunks
#define BIL  40          // LIF burn-in steps

// workspace layout (bytes); ws_size ~2.8GB so plenty of room
#define OFF_WFRAG  ((size_t)0)            // 11*16384 = 180,224
#define OFF_CUR    ((size_t)262144)       // 256000*64*4 = 65,536,000
#define OFF_MASK   ((size_t)65798144)     // 256000*8    =  2,048,000
#define OFF_R      ((size_t)67846144)     // 1000*256*20*4 = 20,480,000
#define OFF_E      ((size_t)88326144)     // 50*5120*4 = 1,024,000
#define OFF_S      ((size_t)89350144)     // 1,024,000
#define OFF_PACC   ((size_t)90374144)     // 1,024,000

// ---------------------------------------------------------------------------
// k0: pack W_h into fragment-ordered split-bf16.
// Per k-tile kt (64 k's): hi region 8192B then lo region 8192B.
// Slot s = (nf*2+kf)*64 + lane holds 8 bf16: h = nf*16+(lane&15),
// k = kt*64 + kf*32 + ((lane>>4)&3)*8 + j.
// ---------------------------------------------------------------------------
__global__ void wprep(const float* __restrict__ Wh, unsigned short* __restrict__ wfrag) {
    int e = blockIdx.x * 256 + threadIdx.x;          // 22*256 = 5632 exact
    int kt   = e >> 9;
    int rem  = e & 511;
    int nf   = rem >> 7;
    int kf   = (rem >> 6) & 1;
    int lane = rem & 63;
    int h     = nf * 16 + (lane & 15);
    int kbase = kt * 64 + kf * 32 + ((lane >> 4) & 3) * 8;
    int slot  = (nf * 2 + kf) * 64 + lane;
    unsigned short* dh = wfrag + (size_t)kt * 8192 + slot * 8;
    unsigned short* dl = dh + 4096;
#pragma unroll
    for (int j = 0; j < 8; ++j) {
        int k = kbase + j;
        float v = (k < K_) ? Wh[(size_t)h * K_ + k] : 0.0f;
        unsigned u  = __builtin_bit_cast(unsigned, v);
        float    fh = __builtin_bit_cast(float, u & 0xffff0000u);
        float    r  = v - fh;
        dh[j] = (unsigned short)(u >> 16);
        dl[j] = (unsigned short)(__builtin_bit_cast(unsigned, r) >> 16);
    }
}

// ---------------------------------------------------------------------------
// k1: GEMM  currents[r][h] = sum_k x[r][k]*W_h[h][k] + b_h[h]
// 128-row tile, 4 waves; wave owns 2 m-frags; W fragments loaded directly
// from global (L1/L2-resident, coalesced); x global->reg, chop-split in regs.
// No LDS, no barriers.
// ---------------------------------------------------------------------------
__device__ __forceinline__ void splitpair(f32x4 p0, f32x4 p1, short8& hi, short8& lo) {
#pragma unroll
    for (int j = 0; j < 4; ++j) {
        {
            unsigned u  = __builtin_bit_cast(unsigned, p0[j]);
            float    fh = __builtin_bit_cast(float, u & 0xffff0000u);
            float    r  = p0[j] - fh;
            hi[j] = (short)(u >> 16);
            lo[j] = (short)(__builtin_bit_cast(unsigned, r) >> 16);
        }
        {
            unsigned u  = __builtin_bit_cast(unsigned, p1[j]);
            float    fh = __builtin_bit_cast(float, u & 0xffff0000u);
            float    r  = p1[j] - fh;
            hi[j + 4] = (short)(u >> 16);
            lo[j + 4] = (short)(__builtin_bit_cast(unsigned, r) >> 16);
        }
    }
}

template <bool GUARD>
__device__ __forceinline__ void gemm_kstep(int kt, int lane, int klane,
                                           const float* xA0, const float* xA1,
                                           const unsigned short* __restrict__ wfrag,
                                           f32x4 (&acc)[2][4]) {
    const short8* wh = (const short8*)(wfrag + (size_t)kt * 8192);
    const short8* wl = (const short8*)(wfrag + (size_t)kt * 8192 + 4096);
    const float* xA[2] = {xA0, xA1};
#pragma unroll
    for (int kf = 0; kf < 2; ++kf) {
        int k0 = kt * 64 + kf * 32 + klane;
        short8 ah[2], al[2];
#pragma unroll
        for (int i = 0; i < 2; ++i) {
            f32x4 p0 = *(const f32x4*)(xA[i] + k0);
            f32x4 p1 = {0.f, 0.f, 0.f, 0.f};
            if (!GUARD || (k0 + 4 < K_)) p1 = *(const f32x4*)(xA[i] + k0 + 4);
            splitpair(p0, p1, ah[i], al[i]);
        }
#pragma unroll
        for (int n = 0; n < 4; ++n) {
            short8 bhf = wh[(n * 2 + kf) * 64 + lane];
            short8 blf = wl[(n * 2 + kf) * 64 + lane];
#pragma unroll
            for (int i = 0; i < 2; ++i) {
                acc[i][n] = __builtin_amdgcn_mfma_f32_16x16x32_bf16(ah[i], bhf, acc[i][n], 0, 0, 0);
                acc[i][n] = __builtin_amdgcn_mfma_f32_16x16x32_bf16(al[i], bhf, acc[i][n], 0, 0, 0);
                acc[i][n] = __builtin_amdgcn_mfma_f32_16x16x32_bf16(ah[i], blf, acc[i][n], 0, 0, 0);
            }
        }
    }
}

__global__ __launch_bounds__(256) void gemm_cur(const float* __restrict__ x,
                                                const unsigned short* __restrict__ wfrag,
                                                const float* __restrict__ b_h,
                                                float* __restrict__ cur) {
    int tid  = threadIdx.x;
    int lane = tid & 63;
    int wid  = tid >> 6;
    int row0 = blockIdx.x * 128;
    int klane = ((lane >> 4) & 3) * 8;

    const float* xA0 = x + (size_t)(row0 + (wid * 2 + 0) * 16 + (lane & 15)) * K_;
    const float* xA1 = x + (size_t)(row0 + (wid * 2 + 1) * 16 + (lane & 15)) * K_;

    float bh4[4];
#pragma unroll
    for (int n = 0; n < 4; ++n) bh4[n] = b_h[n * 16 + (lane & 15)];

    f32x4 acc[2][4];
#pragma unroll
    for (int i = 0; i < 2; ++i)
#pragma unroll
        for (int n = 0; n < 4; ++n) acc[i][n] = (f32x4){0.f, 0.f, 0.f, 0.f};

#pragma unroll 2
    for (int kt = 0; kt < 10; ++kt)
        gemm_kstep<false>(kt, lane, klane, xA0, xA1, wfrag, acc);
    gemm_kstep<true>(10, lane, klane, xA0, xA1, wfrag, acc);

    // epilogue: C/D layout col = lane&15, row = (lane>>4)*4 + j
#pragma unroll
    for (int i = 0; i < 2; ++i) {
        int row = row0 + (wid * 2 + i) * 16 + ((lane >> 4) & 3) * 4;
#pragma unroll
        for (int n = 0; n < 4; ++n) {
#pragma unroll
            for (int j = 0; j < 4; ++j) {
                cur[(size_t)(row + j) * H_ + n * 16 + (lane & 15)] = acc[i][n][j] + bh4[n];
            }
        }
    }
}

// ---------------------------------------------------------------------------
// k2: LIF, chunked speculative. One wave per (batch, chunk); lane = neuron.
// v=(v+cur)/2; spike v>=1; hard reset. Burn-in BIL steps from v=0: error
// <= 3*2^-40 (and any reset during burn-in synchronizes exactly).
// ---------------------------------------------------------------------------
__global__ __launch_bounds__(64) void lif(const float* __restrict__ cur, ull* __restrict__ masks) {
    int b = blockIdx.x & 255;
    int c = blockIdx.x >> 8;
    int h = threadIdx.x;
    int t0 = c * TCL;
    int ts = (c == 0) ? 0 : (t0 - BIL);
    const float* p = cur + ((size_t)b * T_ + ts) * H_ + h;
    ull* mp = masks + (size_t)b * T_;
    float v = 0.0f;
#pragma unroll 4
    for (int t = ts; t < t0; ++t) {
        float cc = *p; p += H_;
        v = (v + cc) * 0.5f;
        v = (v >= 1.0f) ? 0.0f : v;
    }
#pragma unroll 4
    for (int t = t0; t < t0 + TCL; ++t) {
        float cc = *p; p += H_;
        v = (v + cc) * 0.5f;
        bool s = (v >= 1.0f);
        ull m = __ballot(s);
        if (h == 0) mp[t] = m;
        v = s ? 0.0f : v;
    }
}

// ---------------------------------------------------------------------------
// k3: R'[t][b][o] = (1-beta_o)*(b_r[o] + sum_h s[h]*W_r[o][h])
// one thread per (t,b); iterate set bits of the 64-bit spike mask,
// add W_r^T columns (20 floats = 5 x f32x4) from LDS.
// ---------------------------------------------------------------------------
__global__ __launch_bounds__(256) void rin(const ull* __restrict__ masks, const float* __restrict__ Wr,
                                           const float* __restrict__ br, const float* __restrict__ tau,
                                           float* __restrict__ R) {
    __shared__ float wt[64][20];     // transposed: wt[h][o]; rows 80B apart (16B aligned)
    __shared__ float scale[20], base[20];
    int tid = threadIdx.x;
    for (int i = tid; i < 1280; i += 256) wt[i & 63][i >> 6] = Wr[(size_t)(i >> 6) * 64 + (i & 63)];
    if (tid < 20) {
        float beta = 1.0f / (1.0f + __expf(-tau[tid]));
        scale[tid] = 1.0f - beta;
        base[tid]  = br[tid];
    }
    __syncthreads();

    int g = blockIdx.x * 256 + tid;      // 1000 blocks * 256 = 256000 exact
    int t = g >> 8;
    int b = g & 255;
    ull m = masks[(size_t)b * T_ + t];
    f32x4 a[5];
#pragma unroll
    for (int i = 0; i < 5; ++i) a[i] = (f32x4){0.f, 0.f, 0.f, 0.f};
    while (m) {
        int h = __builtin_ctzll(m);
        m &= (m - 1);
        const f32x4* w4 = (const f32x4*)&wt[h][0];
#pragma unroll
        for (int i = 0; i < 5; ++i) a[i] += w4[i];
    }
    f32x4* out = (f32x4*)(R + (size_t)g * 20);
#pragma unroll
    for (int i = 0; i < 5; ++i) {
        f32x4 r;
#pragma unroll
        for (int j = 0; j < 4; ++j) r[j] = scale[i * 4 + j] * (base[i * 4 + j] + a[i][j]);
        out[i] = r;
    }
}

// ---------------------------------------------------------------------------
// k4: per-chunk end state (zero init):  E_c = sum_{j} beta^{TC-1-j} R'[t0+j]
// ---------------------------------------------------------------------------
__global__ __launch_bounds__(64) void scanE(const float* __restrict__ R, const float* __restrict__ tau,
                                            float* __restrict__ E) {
    int c = blockIdx.x >> 2;
    int b = ((blockIdx.x & 3) << 6) | threadIdx.x;
    float beta[20], v[20];
#pragma unroll
    for (int o = 0; o < 20; ++o) { beta[o] = 1.0f / (1.0f + __expf(-tau[o])); v[o] = 0.0f; }
    int t0 = c * TC;
    for (int j = 0; j < TC; ++j) {
        const f32x4* p = (const f32x4*)(R + (size_t)(t0 + j) * 5120 + b * 20);
        f32x4 q[5];
#pragma unroll
        for (int i = 0; i < 5; ++i) q[i] = p[i];
#pragma unroll
        for (int o = 0; o < 20; ++o) v[o] = beta[o] * v[o] + q[o >> 2][o & 3];
    }
    float* e = E + ((size_t)c * 256 + b) * 20;
#pragma unroll
    for (int o = 0; o < 20; ++o) e[o] = v[o];
}

// ---------------------------------------------------------------------------
// k5: carry combine: S_c = beta^TC * S_{c-1} + E_{c-1}, S_0 = 0
// ---------------------------------------------------------------------------
__global__ void carry(const float* __restrict__ E, const float* __restrict__ tau,
                      float* __restrict__ S) {
    int g = blockIdx.x * 256 + threadIdx.x;   // 5120 exact
    int o = g % 20;
    float beta = 1.0f / (1.0f + __expf(-tau[o]));
    float bp = exp2f((float)TC * log2f(beta));
    float s = 0.0f;
    for (int c = 0; c < NC; ++c) {
        S[(size_t)c * 5120 + g] = s;
        s = bp * s + E[(size_t)c * 5120 + g];
    }
}

// ---------------------------------------------------------------------------
// k6: per-chunk scan with softmax accumulation (mask t>10)
// ---------------------------------------------------------------------------
__global__ __launch_bounds__(64) void scanSoft(const float* __restrict__ R, const float* __restrict__ S,
                                               const float* __restrict__ tau, float* __restrict__ pacc) {
    int c = blockIdx.x >> 2;
    int b = ((blockIdx.x & 3) << 6) | threadIdx.x;
    size_t sb = ((size_t)c * 256 + b) * 20;
    float beta[20], v[20], acc[20];
#pragma unroll
    for (int o = 0; o < 20; ++o) {
        beta[o] = 1.0f / (1.0f + __expf(-tau[o]));
        v[o] = S[sb + o];
        acc[o] = 0.0f;
    }
    int t0 = c * TC;
    for (int j = 0; j < TC; ++j) {
        int t = t0 + j;
        const f32x4* p = (const f32x4*)(R + (size_t)t * 5120 + b * 20);
        f32x4 q[5];
#pragma unroll
        for (int i = 0; i < 5; ++i) q[i] = p[i];
#pragma unroll
        for (int o = 0; o < 20; ++o) v[o] = beta[o] * v[o] + q[o >> 2][o & 3];
        if (t >= 11) {
            float mx = v[0];
#pragma unroll
            for (int o = 1; o < 20; ++o) mx = fmaxf(mx, v[o]);
            float e[20], ssum = 0.0f;
#pragma unroll
            for (int o = 0; o < 20; ++o) { e[o] = __expf(v[o] - mx); ssum += e[o]; }
            float inv = 1.0f / ssum;
#pragma unroll
            for (int o = 0; o < 20; ++o) acc[o] += e[o] * inv;
        }
    }
#pragma unroll
    for (int o = 0; o < 20; ++o) pacc[sb + o] = acc[o];
}

// ---------------------------------------------------------------------------
// k7: reduce chunk partials
// ---------------------------------------------------------------------------
__global__ void reduceAcc(const float* __restrict__ pacc, float* __restrict__ out) {
    int g = blockIdx.x * 256 + threadIdx.x;   // 5120 exact
    float s = 0.0f;
    for (int c = 0; c < NC; ++c) s += pacc[(size_t)c * 5120 + g];
    out[g] = s;
}

// ---------------------------------------------------------------------------
extern "C" void kernel_launch(void* const* d_in, const int* in_sizes, int n_in,
                              void* d_out, int out_size, void* d_ws, size_t ws_size,
                              hipStream_t stream) {
    const float* x   = (const float*)d_in[0];
    const float* W_h = (const float*)d_in[1];
    const float* b_h = (const float*)d_in[2];
    const float* W_r = (const float*)d_in[3];
    const float* b_r = (const float*)d_in[4];
    const float* tau = (const float*)d_in[5];

    char* ws = (char*)d_ws;
    unsigned short* wfrag = (unsigned short*)(ws + OFF_WFRAG);
    float* cur  = (float*)(ws + OFF_CUR);
    ull*   msk  = (ull*)(ws + OFF_MASK);
    float* R    = (float*)(ws + OFF_R);
    float* E    = (float*)(ws + OFF_E);
    float* S    = (float*)(ws + OFF_S);
    float* pacc = (float*)(ws + OFF_PACC);
    float* out  = (float*)d_out;

    wprep<<<22, 256, 0, stream>>>(W_h, wfrag);
    gemm_cur<<<2000, 256, 0, stream>>>(x, wfrag, b_h, cur);
    lif<<<NCL * 256, 64, 0, stream>>>(cur, msk);
    rin<<<1000, 256, 0, stream>>>(msk, W_r, b_r, tau, R);
    scanE<<<NC * 4, 64, 0, stream>>>(R, tau, E);
    carry<<<20, 256, 0, stream>>>(E, tau, S);
    scanSoft<<<NC * 4, 64, 0, stream>>>(R, S, tau, pacc);
    reduceAcc<<<20, 256, 0, stream>>>(pacc, out);
}

// Round 3
// 335.176 us; speedup vs baseline: 2.0072x; 1.0279x over previous
//
#include <hip/hip_runtime.h>

// ---------------------------------------------------------------------------
// VanillaSFNN: x[256,1000,700] -> currents GEMM -> LIF spikes -> readout leaky
// integrator + softmax accumulation.
//
// Pipeline (7 launches):
//   k0 wprep   : W_h f32 -> split bf16 hi/lo packed in MFMA fragment order
//   k1 gemm    : currents via 3-term split-bf16 MFMA; wave owns 4 m-frags
//   k2 lif     : chunked speculative scan (burn-in 40), spikes -> ballot masks
//   k3 scanE   : per T-chunk end-state of v_ro recurrence, R' recomputed from
//                masks (set-bit iteration), 4 outputs per thread
//   k4 carry   : sequential chunk-carry combine per (b,o)
//   k5 scanSoft: per-chunk v_ro scan + softmax accumulation (t>10 mask),
//                R' recomputed from masks
//   k6 reduce  : sum chunk partials -> d_out[b][o]
// ---------------------------------------------------------------------------

typedef float  f32x4  __attribute__((ext_vector_type(4)));
typedef short  short8 __attribute__((ext_vector_type(8)));
typedef unsigned long long ull;

#define B_   256
#define T_   1000
#define K_   700
#define H_   64
#define O_   20
#define TC   10          // v_ro scan chunk length
#define NC   100         // number of v_ro chunks
#define TCL  100         // LIF chunk length
#define NCL  10          // LIF chunks
#define BIL  40          // LIF burn-in steps

// workspace layout (bytes); ws ~2.8GB
#define OFF_WFRAG  ((size_t)0)            // 11*16384 = 180,224
#define OFF_CUR    ((size_t)262144)       // 256000*64*4 = 65,536,000
#define OFF_MASK   ((size_t)65798144)     // 256000*8    =  2,048,000
#define OFF_E      ((size_t)67846144)     // 100*5120*4 = 2,048,000
#define OFF_S      ((size_t)69943296)
#define OFF_PACC   ((size_t)72040448)

// ---------------------------------------------------------------------------
// k0: pack W_h into fragment-ordered split-bf16 (zero-padded past k=700).
// ---------------------------------------------------------------------------
__global__ void wprep(const float* __restrict__ Wh, unsigned short* __restrict__ wfrag) {
    int e = blockIdx.x * 256 + threadIdx.x;          // 22*256 = 5632 exact
    int kt   = e >> 9;
    int rem  = e & 511;
    int nf   = rem >> 7;
    int kf   = (rem >> 6) & 1;
    int lane = rem & 63;
    int h     = nf * 16 + (lane & 15);
    int kbase = kt * 64 + kf * 32 + ((lane >> 4) & 3) * 8;
    int slot  = (nf * 2 + kf) * 64 + lane;
    unsigned short* dh = wfrag + (size_t)kt * 8192 + slot * 8;
    unsigned short* dl = dh + 4096;
#pragma unroll
    for (int j = 0; j < 8; ++j) {
        int k = kbase + j;
        float v = (k < K_) ? Wh[(size_t)h * K_ + k] : 0.0f;
        unsigned u  = __builtin_bit_cast(unsigned, v);
        float    fh = __builtin_bit_cast(float, u & 0xffff0000u);
        float    r  = v - fh;
        dh[j] = (unsigned short)(u >> 16);
        dl[j] = (unsigned short)(__builtin_bit_cast(unsigned, r) >> 16);
    }
}

// ---------------------------------------------------------------------------
// k1: GEMM  currents[r][h] = sum_k x[r][k]*W_h[h][k] + b_h[h]
// 128-row blocks, 2 waves; wave owns 4 m-frags (64 rows). W fragments loaded
// directly from global (L2-resident), x global->reg chop-split. No LDS.
// ---------------------------------------------------------------------------
__device__ __forceinline__ void splitpair(f32x4 p0, f32x4 p1, short8& hi, short8& lo) {
#pragma unroll
    for (int j = 0; j < 4; ++j) {
        {
            unsigned u  = __builtin_bit_cast(unsigned, p0[j]);
            float    fh = __builtin_bit_cast(float, u & 0xffff0000u);
            float    r  = p0[j] - fh;
            hi[j] = (short)(u >> 16);
            lo[j] = (short)(__builtin_bit_cast(unsigned, r) >> 16);
        }
        {
            unsigned u  = __builtin_bit_cast(unsigned, p1[j]);
            float    fh = __builtin_bit_cast(float, u & 0xffff0000u);
            float    r  = p1[j] - fh;
            hi[j + 4] = (short)(u >> 16);
            lo[j + 4] = (short)(__builtin_bit_cast(unsigned, r) >> 16);
        }
    }
}

template <bool GUARD>
__device__ __forceinline__ void gemm_kstep(int kt, int lane, int klane,
                                           const float* const (&xA)[4],
                                           const unsigned short* __restrict__ wfrag,
                                           f32x4 (&acc)[4][4]) {
    const short8* wh = (const short8*)(wfrag + (size_t)kt * 8192);
    const short8* wl = (const short8*)(wfrag + (size_t)kt * 8192 + 4096);
#pragma unroll
    for (int kf = 0; kf < 2; ++kf) {
        int k0 = kt * 64 + kf * 32 + klane;
        short8 ah[4], al[4];
#pragma unroll
        for (int i = 0; i < 4; ++i) {
            f32x4 p0 = *(const f32x4*)(xA[i] + k0);
            f32x4 p1 = {0.f, 0.f, 0.f, 0.f};
            if (!GUARD || (k0 + 4 < K_)) p1 = *(const f32x4*)(xA[i] + k0 + 4);
            splitpair(p0, p1, ah[i], al[i]);
        }
#pragma unroll
        for (int n = 0; n < 4; ++n) {
            short8 bhf = wh[(n * 2 + kf) * 64 + lane];
            short8 blf = wl[(n * 2 + kf) * 64 + lane];
#pragma unroll
            for (int i = 0; i < 4; ++i) {
                acc[i][n] = __builtin_amdgcn_mfma_f32_16x16x32_bf16(ah[i], bhf, acc[i][n], 0, 0, 0);
                acc[i][n] = __builtin_amdgcn_mfma_f32_16x16x32_bf16(al[i], bhf, acc[i][n], 0, 0, 0);
                acc[i][n] = __builtin_amdgcn_mfma_f32_16x16x32_bf16(ah[i], blf, acc[i][n], 0, 0, 0);
            }
        }
    }
}

__global__ __launch_bounds__(128) void gemm_cur(const float* __restrict__ x,
                                                const unsigned short* __restrict__ wfrag,
                                                const float* __restrict__ b_h,
                                                float* __restrict__ cur) {
    int tid  = threadIdx.x;
    int lane = tid & 63;
    int wid  = tid >> 6;                       // 0..1
    int row0 = blockIdx.x * 128 + wid * 64;
    int klane = ((lane >> 4) & 3) * 8;

    const float* xA[4];
#pragma unroll
    for (int i = 0; i < 4; ++i) xA[i] = x + (size_t)(row0 + i * 16 + (lane & 15)) * K_;

    float bh4[4];
#pragma unroll
    for (int n = 0; n < 4; ++n) bh4[n] = b_h[n * 16 + (lane & 15)];

    f32x4 acc[4][4];
#pragma unroll
    for (int i = 0; i < 4; ++i)
#pragma unroll
        for (int n = 0; n < 4; ++n) acc[i][n] = (f32x4){0.f, 0.f, 0.f, 0.f};

#pragma unroll 2
    for (int kt = 0; kt < 10; ++kt)
        gemm_kstep<false>(kt, lane, klane, xA, wfrag, acc);
    gemm_kstep<true>(10, lane, klane, xA, wfrag, acc);

    // epilogue: C/D layout col = lane&15, row = (lane>>4)*4 + j
#pragma unroll
    for (int i = 0; i < 4; ++i) {
        int row = row0 + i * 16 + ((lane >> 4) & 3) * 4;
#pragma unroll
        for (int n = 0; n < 4; ++n) {
#pragma unroll
            for (int j = 0; j < 4; ++j) {
                cur[(size_t)(row + j) * H_ + n * 16 + (lane & 15)] = acc[i][n][j] + bh4[n];
            }
        }
    }
}

// ---------------------------------------------------------------------------
// k2: LIF, chunked speculative. One wave per (batch, chunk); lane = neuron.
// ---------------------------------------------------------------------------
__global__ __launch_bounds__(64) void lif(const float* __restrict__ cur, ull* __restrict__ masks) {
    int b = blockIdx.x & 255;
    int c = blockIdx.x >> 8;
    int h = threadIdx.x;
    int t0 = c * TCL;
    int ts = (c == 0) ? 0 : (t0 - BIL);
    const float* p = cur + ((size_t)b * T_ + ts) * H_ + h;
    ull* mp = masks + (size_t)b * T_;
    float v = 0.0f;
#pragma unroll 4
    for (int t = ts; t < t0; ++t) {
        float cc = *p; p += H_;
        v = (v + cc) * 0.5f;
        v = (v >= 1.0f) ? 0.0f : v;
    }
#pragma unroll 4
    for (int t = t0; t < t0 + TCL; ++t) {
        float cc = *p; p += H_;
        v = (v + cc) * 0.5f;
        bool s = (v >= 1.0f);
        ull m = __ballot(s);
        if (h == 0) mp[t] = m;
        v = s ? 0.0f : v;
    }
}

// ---------------------------------------------------------------------------
// k3: scanE — chunk end-state of v = beta*v + (1-beta)*(b_r + spikes.W_r),
// zero init. Thread = (chunk c, batch b, o-quad o4); R' recomputed from masks.
// ---------------------------------------------------------------------------
__global__ __launch_bounds__(256) void scanE(const ull* __restrict__ masks,
                                             const float* __restrict__ Wr,
                                             const float* __restrict__ br,
                                             const float* __restrict__ tau,
                                             float* __restrict__ E) {
    __shared__ __align__(16) float wt[64][20];   // wt[h][o]
    __shared__ __align__(16) float sScale[20], sBase[20], sBeta[20];
    int tid = threadIdx.x;
    for (int i = tid; i < 1280; i += 256) wt[i & 63][i >> 6] = Wr[(size_t)(i >> 6) * 64 + (i & 63)];
    if (tid < 20) {
        float beta = 1.0f / (1.0f + __expf(-tau[tid]));
        sBeta[tid]  = beta;
        sScale[tid] = 1.0f - beta;
        sBase[tid]  = br[tid];
    }
    __syncthreads();

    int g  = blockIdx.x * 256 + tid;   // 500*256 = 128000 exact = 100*256*5
    int o4 = g % 5;
    int cb = g / 5;
    int b  = cb & 255;
    int c  = cb >> 8;

    f32x4 beta4  = *(const f32x4*)&sBeta[o4 * 4];
    f32x4 scale4 = *(const f32x4*)&sScale[o4 * 4];
    f32x4 base4  = *(const f32x4*)&sBase[o4 * 4];

    f32x4 v = {0.f, 0.f, 0.f, 0.f};
    int t0 = c * TC;
    const ull* mp = masks + (size_t)b * T_ + t0;
    for (int j = 0; j < TC; ++j) {
        ull m = mp[j];
        f32x4 a = {0.f, 0.f, 0.f, 0.f};
        while (m) {
            int h = __builtin_ctzll(m);
            m &= (m - 1);
            a += *(const f32x4*)&wt[h][o4 * 4];
        }
        f32x4 q;
#pragma unroll
        for (int jj = 0; jj < 4; ++jj) q[jj] = scale4[jj] * (base4[jj] + a[jj]);
        v = beta4 * v + q;
    }
    *(f32x4*)(E + (size_t)cb * 20 + o4 * 4) = v;
}

// ---------------------------------------------------------------------------
// k4: carry combine: S_c = beta^TC * S_{c-1} + E_{c-1}, S_0 = 0
// ---------------------------------------------------------------------------
__global__ __launch_bounds__(64) void carry(const float* __restrict__ E, const float* __restrict__ tau,
                                            float* __restrict__ S) {
    int g = blockIdx.x * 64 + threadIdx.x;   // 80*64 = 5120 exact
    int o = g % 20;
    float beta = 1.0f / (1.0f + __expf(-tau[o]));
    float bp = 1.0f;
#pragma unroll
    for (int i = 0; i < TC; ++i) bp *= beta;
    float s = 0.0f;
#pragma unroll 4
    for (int c = 0; c < NC; ++c) {
        S[(size_t)c * 5120 + g] = s;
        s = bp * s + E[(size_t)c * 5120 + g];
    }
}

// ---------------------------------------------------------------------------
// k5: per-chunk scan with softmax accumulation (t>10 mask); R' from masks.
// Thread = (c,b), all 20 outputs.
// ---------------------------------------------------------------------------
__global__ __launch_bounds__(64) void scanSoft(const ull* __restrict__ masks,
                                               const float* __restrict__ Wr,
                                               const float* __restrict__ br,
                                               const float* __restrict__ tau,
                                               const float* __restrict__ S,
                                               float* __restrict__ pacc) {
    __shared__ __align__(16) float wt[64][20];
    __shared__ __align__(16) float sScale[20], sBase[20], sBeta[20];
    int tid = threadIdx.x;
    for (int i = tid; i < 1280; i += 64) wt[i & 63][i >> 6] = Wr[(size_t)(i >> 6) * 64 + (i & 63)];
    if (tid < 20) {
        float beta = 1.0f / (1.0f + __expf(-tau[tid]));
        sBeta[tid]  = beta;
        sScale[tid] = 1.0f - beta;
        sBase[tid]  = br[tid];
    }
    __syncthreads();

    int g = blockIdx.x * 64 + tid;   // 400*64 = 25600 exact = 100*256
    int b = g & 255;
    int c = g >> 8;
    size_t sb = (size_t)g * 20;

    float beta[20], v[20], acc[20];
#pragma unroll
    for (int o = 0; o < 20; ++o) {
        beta[o] = sBeta[o];
        v[o]   = S[sb + o];
        acc[o] = 0.0f;
    }
    int t0 = c * TC;
    const ull* mp = masks + (size_t)b * T_ + t0;
    for (int j = 0; j < TC; ++j) {
        int t = t0 + j;
        ull m = mp[j];
        f32x4 a[5];
#pragma unroll
        for (int i = 0; i < 5; ++i) a[i] = (f32x4){0.f, 0.f, 0.f, 0.f};
        while (m) {
            int h = __builtin_ctzll(m);
            m &= (m - 1);
            const f32x4* w4 = (const f32x4*)&wt[h][0];
#pragma unroll
            for (int i = 0; i < 5; ++i) a[i] += w4[i];
        }
#pragma unroll
        for (int o = 0; o < 20; ++o) {
            float q = sScale[o] * (sBase[o] + a[o >> 2][o & 3]);
            v[o] = beta[o] * v[o] + q;
        }
        if (t >= 11) {
            float mx = v[0];
#pragma unroll
            for (int o = 1; o < 20; ++o) mx = fmaxf(mx, v[o]);
            float e[20], ssum = 0.0f;
#pragma unroll
            for (int o = 0; o < 20; ++o) { e[o] = __expf(v[o] - mx); ssum += e[o]; }
            float inv = 1.0f / ssum;
#pragma unroll
            for (int o = 0; o < 20; ++o) acc[o] += e[o] * inv;
        }
    }
#pragma unroll
    for (int o = 0; o < 20; ++o) pacc[sb + o] = acc[o];
}

// ---------------------------------------------------------------------------
// k6: reduce chunk partials
// ---------------------------------------------------------------------------
__global__ __launch_bounds__(64) void reduceAcc(const float* __restrict__ pacc, float* __restrict__ out) {
    int g = blockIdx.x * 64 + threadIdx.x;   // 80*64 = 5120 exact
    float s = 0.0f;
#pragma unroll 4
    for (int c = 0; c < NC; ++c) s += pacc[(size_t)c * 5120 + g];
    out[g] = s;
}

// ---------------------------------------------------------------------------
extern "C" void kernel_launch(void* const* d_in, const int* in_sizes, int n_in,
                              void* d_out, int out_size, void* d_ws, size_t ws_size,
                              hipStream_t stream) {
    const float* x   = (const float*)d_in[0];
    const float* W_h = (const float*)d_in[1];
    const float* b_h = (const float*)d_in[2];
    const float* W_r = (const float*)d_in[3];
    const float* b_r = (const float*)d_in[4];
    const float* tau = (const float*)d_in[5];

    char* ws = (char*)d_ws;
    unsigned short* wfrag = (unsigned short*)(ws + OFF_WFRAG);
    float* cur  = (float*)(ws + OFF_CUR);
    ull*   msk  = (ull*)(ws + OFF_MASK);
    float* E    = (float*)(ws + OFF_E);
    float* S    = (float*)(ws + OFF_S);
    float* pacc = (float*)(ws + OFF_PACC);
    float* out  = (float*)d_out;

    wprep<<<22, 256, 0, stream>>>(W_h, wfrag);
    gemm_cur<<<2000, 128, 0, stream>>>(x, wfrag, b_h, cur);
    lif<<<NCL * 256, 64, 0, stream>>>(cur, msk);
    scanE<<<500, 256, 0, stream>>>(msk, W_r, b_r, tau, E);
    carry<<<80, 64, 0, stream>>>(E, tau, S);
    scanSoft<<<400, 64, 0, stream>>>(msk, W_r, b_r, tau, S, pacc);
    reduceAcc<<<80, 64, 0, stream>>>(pacc, out);
}

// Round 4
// 286.059 us; speedup vs baseline: 2.3519x; 1.1717x over previous
//
#include <hip/hip_runtime.h>

// ---------------------------------------------------------------------------
// VanillaSFNN: x[256,1000,700] -> currents GEMM -> LIF spikes -> readout leaky
// integrator + softmax accumulation.
//
// Pipeline (4 launches):
//   k0 wprep  : W_h f32 -> split bf16 hi/lo packed in MFMA fragment order
//   k1 gemm   : currents via 3-term split-bf16 MFMA; x staged to LDS via
//               global_load_lds (double-buffered, XOR-swizzled)
//   k2 lif    : chunked speculative scan (burn-in 40), spikes -> ballot masks
//   k3 readout: per-batch fused scanE + carry + scanSoft + reduce (all LDS)
// ---------------------------------------------------------------------------

typedef float  f32x4  __attribute__((ext_vector_type(4)));
typedef short  short8 __attribute__((ext_vector_type(8)));
typedef unsigned long long ull;

#define B_   256
#define T_   1000
#define K_   700
#define H_   64
#define O_   20
#define TC   10          // v_ro scan chunk length
#define NC   100         // number of v_ro chunks
#define TCL  100         // LIF chunk length
#define NCL  10          // LIF chunks
#define BIL  40          // LIF burn-in steps

// workspace layout (bytes)
#define OFF_WFRAG  ((size_t)0)            // 11*16384 = 180,224
#define OFF_CUR    ((size_t)262144)       // 256000*64*4 = 65,536,000
#define OFF_MASK   ((size_t)65798144)     // 256000*8    =  2,048,000

// ---------------------------------------------------------------------------
// k0: pack W_h into fragment-ordered split-bf16 (zero-padded past k=700).
// ---------------------------------------------------------------------------
__global__ void wprep(const float* __restrict__ Wh, unsigned short* __restrict__ wfrag) {
    int e = blockIdx.x * 256 + threadIdx.x;          // 22*256 = 5632 exact
    int kt   = e >> 9;
    int rem  = e & 511;
    int nf   = rem >> 7;
    int kf   = (rem >> 6) & 1;
    int lane = rem & 63;
    int h     = nf * 16 + (lane & 15);
    int kbase = kt * 64 + kf * 32 + ((lane >> 4) & 3) * 8;
    int slot  = (nf * 2 + kf) * 64 + lane;
    unsigned short* dh = wfrag + (size_t)kt * 8192 + slot * 8;
    unsigned short* dl = dh + 4096;
#pragma unroll
    for (int j = 0; j < 8; ++j) {
        int k = kbase + j;
        float v = (k < K_) ? Wh[(size_t)h * K_ + k] : 0.0f;
        unsigned u  = __builtin_bit_cast(unsigned, v);
        float    fh = __builtin_bit_cast(float, u & 0xffff0000u);
        float    r  = v - fh;
        dh[j] = (unsigned short)(u >> 16);
        dl[j] = (unsigned short)(__builtin_bit_cast(unsigned, r) >> 16);
    }
}

// ---------------------------------------------------------------------------
// k1: GEMM  currents[r][h] = sum_k x[r][k]*W_h[h][k] + b_h[h]
// 256 threads (4 waves), 128-row tile, BK=64. x staged global->LDS via
// global_load_lds dwordx4, double-buffered; source pre-XOR-swizzled with
// ((row&7)<<4) so swizzled ds_read_b128 is ~2-way conflict-free.
// W fragments loaded directly from global (L2-resident). Wave owns 2 m-frags.
// ---------------------------------------------------------------------------
__device__ __forceinline__ void glds16(const void* src, void* lds) {
    __builtin_amdgcn_global_load_lds(
        (const __attribute__((address_space(1))) void*)src,
        (__attribute__((address_space(3))) void*)lds, 16, 0, 0);
}

__device__ __forceinline__ void splitpair(f32x4 p0, f32x4 p1, short8& hi, short8& lo) {
#pragma unroll
    for (int j = 0; j < 4; ++j) {
        {
            unsigned u  = __builtin_bit_cast(unsigned, p0[j]);
            float    fh = __builtin_bit_cast(float, u & 0xffff0000u);
            float    r  = p0[j] - fh;
            hi[j] = (short)(u >> 16);
            lo[j] = (short)(__builtin_bit_cast(unsigned, r) >> 16);
        }
        {
            unsigned u  = __builtin_bit_cast(unsigned, p1[j]);
            float    fh = __builtin_bit_cast(float, u & 0xffff0000u);
            float    r  = p1[j] - fh;
            hi[j + 4] = (short)(u >> 16);
            lo[j + 4] = (short)(__builtin_bit_cast(unsigned, r) >> 16);
        }
    }
}

// stage one 32KB x-tile (128 rows x 64 k) for k-tile kt into sbuf (swizzled)
__device__ __forceinline__ void stage_x(const float* __restrict__ x, size_t row0,
                                        int kt, int lane, int wid, float* sbuf) {
    int rl = lane >> 4;            // 0..3
    int cl = (lane & 15) * 16;     // 0..240 (byte col in LDS row)
#pragma unroll
    for (int j = 0; j < 8; ++j) {
        int seg = wid * 8 + j;                   // 0..31, 4 rows each
        int r   = seg * 4 + rl;                  // 0..127
        int csrc = cl ^ ((r & 7) << 4);          // pre-swizzled source col
        int kbyte = kt * 256 + csrc;
        if (kbyte + 16 > K_ * 4) kbyte = 0;      // tail clamp; value * W_pad(0) = 0
        const char* src = (const char*)(x + (row0 + r) * (size_t)K_) + kbyte;
        float* dst = sbuf + (size_t)seg * 256;   // wave-uniform base; lane*16B auto
        glds16(src, dst);
    }
}

template <int KT>
__device__ __forceinline__ void gemm_compute(const float* sbuf, int lane, int wid,
                                             const unsigned short* __restrict__ wfrag,
                                             f32x4 (&acc)[2][4]) {
    const short8* wh = (const short8*)(wfrag + (size_t)KT * 8192);
    const short8* wl = (const short8*)(wfrag + (size_t)KT * 8192 + 4096);
    int s = (lane & 7) << 4;
#pragma unroll
    for (int kf = 0; kf < 2; ++kf) {
        int cf = kf * 128 + ((lane >> 4) & 3) * 32;
        short8 ah[2], al[2];
#pragma unroll
        for (int i = 0; i < 2; ++i) {
            int rloc = wid * 32 + i * 16 + (lane & 15);
            const char* base = (const char*)sbuf + rloc * 256;
            f32x4 p0 = *(const f32x4*)(base + (cf ^ s));
            f32x4 p1 = *(const f32x4*)(base + ((cf + 16) ^ s));
            splitpair(p0, p1, ah[i], al[i]);
        }
#pragma unroll
        for (int n = 0; n < 4; ++n) {
            short8 bhf = wh[(n * 2 + kf) * 64 + lane];
            short8 blf = wl[(n * 2 + kf) * 64 + lane];
#pragma unroll
            for (int i = 0; i < 2; ++i) {
                acc[i][n] = __builtin_amdgcn_mfma_f32_16x16x32_bf16(ah[i], bhf, acc[i][n], 0, 0, 0);
                acc[i][n] = __builtin_amdgcn_mfma_f32_16x16x32_bf16(al[i], bhf, acc[i][n], 0, 0, 0);
                acc[i][n] = __builtin_amdgcn_mfma_f32_16x16x32_bf16(ah[i], blf, acc[i][n], 0, 0, 0);
            }
        }
    }
}

__global__ __launch_bounds__(256) void gemm_cur(const float* __restrict__ x,
                                                const unsigned short* __restrict__ wfrag,
                                                const float* __restrict__ b_h,
                                                float* __restrict__ cur) {
    __shared__ float sbx[2][8192];   // 2 x 32 KB x-tiles
    int tid  = threadIdx.x;
    int lane = tid & 63;
    int wid  = tid >> 6;             // 0..3
    size_t row0 = (size_t)blockIdx.x * 128;

    float bh4[4];
#pragma unroll
    for (int n = 0; n < 4; ++n) bh4[n] = b_h[n * 16 + (lane & 15)];

    f32x4 acc[2][4];
#pragma unroll
    for (int i = 0; i < 2; ++i)
#pragma unroll
        for (int n = 0; n < 4; ++n) acc[i][n] = (f32x4){0.f, 0.f, 0.f, 0.f};

    stage_x(x, row0, 0, lane, wid, sbx[0]);

#define GEMM_STEP(KT)                                                        \
    {                                                                        \
        __syncthreads(); /* drains glds of buf[KT&1] + barrier */            \
        if (KT < 10) stage_x(x, row0, KT + 1, lane, wid,                     \
                             ((KT & 1) ? sbx[0] : sbx[1]));                  \
        gemm_compute<KT>(((KT & 1) ? sbx[1] : sbx[0]), lane, wid, wfrag, acc);\
    }
    GEMM_STEP(0)  GEMM_STEP(1)  GEMM_STEP(2)  GEMM_STEP(3)
    GEMM_STEP(4)  GEMM_STEP(5)  GEMM_STEP(6)  GEMM_STEP(7)
    GEMM_STEP(8)  GEMM_STEP(9)  GEMM_STEP(10)
#undef GEMM_STEP

    // epilogue: C/D layout col = lane&15, row = (lane>>4)*4 + j
#pragma unroll
    for (int i = 0; i < 2; ++i) {
        size_t row = row0 + wid * 32 + i * 16 + ((lane >> 4) & 3) * 4;
#pragma unroll
        for (int n = 0; n < 4; ++n) {
#pragma unroll
            for (int j = 0; j < 4; ++j) {
                cur[(row + j) * H_ + n * 16 + (lane & 15)] = acc[i][n][j] + bh4[n];
            }
        }
    }
}

// ---------------------------------------------------------------------------
// k2: LIF, chunked speculative. One wave per (batch, chunk); lane = neuron.
// ---------------------------------------------------------------------------
__global__ __launch_bounds__(64) void lif(const float* __restrict__ cur, ull* __restrict__ masks) {
    int b = blockIdx.x & 255;
    int c = blockIdx.x >> 8;
    int h = threadIdx.x;
    int t0 = c * TCL;
    int ts = (c == 0) ? 0 : (t0 - BIL);
    const float* p = cur + ((size_t)b * T_ + ts) * H_ + h;
    ull* mp = masks + (size_t)b * T_;
    float v = 0.0f;
#pragma unroll 8
    for (int t = ts; t < t0; ++t) {
        float cc = *p; p += H_;
        v = (v + cc) * 0.5f;
        v = (v >= 1.0f) ? 0.0f : v;
    }
#pragma unroll 8
    for (int t = t0; t < t0 + TCL; ++t) {
        float cc = *p; p += H_;
        v = (v + cc) * 0.5f;
        bool s = (v >= 1.0f);
        ull m = __ballot(s);
        if (h == 0) mp[t] = m;
        v = s ? 0.0f : v;
    }
}

// ---------------------------------------------------------------------------
// k3: fused readout, one block per batch (128 threads). All phases in LDS,
// float-op order identical to the previous scanE/carry/scanSoft/reduce chain.
// ---------------------------------------------------------------------------
__global__ __launch_bounds__(128) void readout(const ull* __restrict__ masks,
                                               const float* __restrict__ Wr,
                                               const float* __restrict__ br,
                                               const float* __restrict__ tau,
                                               float* __restrict__ out) {
    __shared__ __align__(16) float wt[64][20];     // wt[h][o]
    __shared__ ull  smask[T_];
    __shared__ __align__(16) float E[NC][20];
    __shared__ __align__(16) float Sv[NC][20];
    __shared__ __align__(16) float pacc[NC][20];
    __shared__ __align__(16) float sScale[20], sBase[20], sBeta[20];

    int tid = threadIdx.x;
    int b   = blockIdx.x;
    for (int i = tid; i < 1280; i += 128) wt[i & 63][i >> 6] = Wr[(size_t)(i >> 6) * 64 + (i & 63)];
    for (int i = tid; i < T_; i += 128) smask[i] = masks[(size_t)b * T_ + i];
    if (tid < 20) {
        float beta = 1.0f / (1.0f + __expf(-tau[tid]));
        sBeta[tid]  = beta;
        sScale[tid] = 1.0f - beta;
        sBase[tid]  = br[tid];
    }
    __syncthreads();

    // phase 1: scanE — items (c, o4), 500 total
    for (int it = tid; it < NC * 5; it += 128) {
        int o4 = it % 5;
        int c  = it / 5;
        f32x4 beta4  = *(const f32x4*)&sBeta[o4 * 4];
        f32x4 scale4 = *(const f32x4*)&sScale[o4 * 4];
        f32x4 base4  = *(const f32x4*)&sBase[o4 * 4];
        f32x4 v = {0.f, 0.f, 0.f, 0.f};
        const ull* mp = smask + c * TC;
        for (int j = 0; j < TC; ++j) {
            ull m = mp[j];
            f32x4 a = {0.f, 0.f, 0.f, 0.f};
            while (m) {
                int h = __builtin_ctzll(m);
                m &= (m - 1);
                a += *(const f32x4*)&wt[h][o4 * 4];
            }
            f32x4 q;
#pragma unroll
            for (int jj = 0; jj < 4; ++jj) q[jj] = scale4[jj] * (base4[jj] + a[jj]);
            v = beta4 * v + q;
        }
        *(f32x4*)&E[c][o4 * 4] = v;
    }
    __syncthreads();

    // phase 2: carry
    if (tid < 20) {
        int o = tid;
        float beta = sBeta[o];
        float bp = 1.0f;
#pragma unroll
        for (int i = 0; i < TC; ++i) bp *= beta;
        float s = 0.0f;
        for (int c = 0; c < NC; ++c) {
            Sv[c][o] = s;
            s = bp * s + E[c][o];
        }
    }
    __syncthreads();

    // phase 3: scanSoft — thread c < 100
    if (tid < NC) {
        int c = tid;
        float beta[20], v[20], acc[20];
#pragma unroll
        for (int o = 0; o < 20; ++o) {
            beta[o] = sBeta[o];
            v[o]   = Sv[c][o];
            acc[o] = 0.0f;
        }
        int t0 = c * TC;
        const ull* mp = smask + t0;
        for (int j = 0; j < TC; ++j) {
            int t = t0 + j;
            ull m = mp[j];
            f32x4 a[5];
#pragma unroll
            for (int i = 0; i < 5; ++i) a[i] = (f32x4){0.f, 0.f, 0.f, 0.f};
            while (m) {
                int h = __builtin_ctzll(m);
                m &= (m - 1);
                const f32x4* w4 = (const f32x4*)&wt[h][0];
#pragma unroll
                for (int i = 0; i < 5; ++i) a[i] += w4[i];
            }
#pragma unroll
            for (int o = 0; o < 20; ++o) {
                float q = sScale[o] * (sBase[o] + a[o >> 2][o & 3]);
                v[o] = beta[o] * v[o] + q;
            }
            if (t >= 11) {
                float mx = v[0];
#pragma unroll
                for (int o = 1; o < 20; ++o) mx = fmaxf(mx, v[o]);
                float e[20], ssum = 0.0f;
#pragma unroll
                for (int o = 0; o < 20; ++o) { e[o] = __expf(v[o] - mx); ssum += e[o]; }
                float inv = 1.0f / ssum;
#pragma unroll
                for (int o = 0; o < 20; ++o) acc[o] += e[o] * inv;
            }
        }
#pragma unroll
        for (int o = 0; o < 20; ++o) pacc[c][o] = acc[o];
    }
    __syncthreads();

    // phase 4: reduce (ascending c, same order as before)
    if (tid < 20) {
        float s = 0.0f;
        for (int c = 0; c < NC; ++c) s += pacc[c][tid];
        out[(size_t)b * 20 + tid] = s;
    }
}

// ---------------------------------------------------------------------------
extern "C" void kernel_launch(void* const* d_in, const int* in_sizes, int n_in,
                              void* d_out, int out_size, void* d_ws, size_t ws_size,
                              hipStream_t stream) {
    const float* x   = (const float*)d_in[0];
    const float* W_h = (const float*)d_in[1];
    const float* b_h = (const float*)d_in[2];
    const float* W_r = (const float*)d_in[3];
    const float* b_r = (const float*)d_in[4];
    const float* tau = (const float*)d_in[5];

    char* ws = (char*)d_ws;
    unsigned short* wfrag = (unsigned short*)(ws + OFF_WFRAG);
    float* cur  = (float*)(ws + OFF_CUR);
    ull*   msk  = (ull*)(ws + OFF_MASK);
    float* out  = (float*)d_out;

    wprep<<<22, 256, 0, stream>>>(W_h, wfrag);
    gemm_cur<<<2000, 256, 0, stream>>>(x, wfrag, b_h, cur);
    lif<<<NCL * 256, 64, 0, stream>>>(cur, msk);
    readout<<<256, 128, 0, stream>>>(msk, W_r, b_r, tau, out);
}

// Round 5
// 264.853 us; speedup vs baseline: 2.5402x; 1.0801x over previous
//
#include <hip/hip_runtime.h>

// ---------------------------------------------------------------------------
// VanillaSFNN: x[256,1000,700] -> currents GEMM -> LIF spikes -> readout leaky
// integrator + softmax accumulation.
//
// Pipeline (4 launches):
//   k0 wprep  : W_h f32 -> split bf16 hi/lo packed in MFMA fragment order (BK=32)
//   k1 gemm   : currents via 3-term split-bf16 MFMA; x AND W staged to LDS via
//               global_load_lds, depth-3 ring, counted vmcnt (never 0 in loop)
//   k2 lif    : chunked speculative scan (burn-in 40), spikes -> ballot masks
//   k3 readout: per-batch fused scanE + carry + scanSoft + reduce (all LDS)
// ---------------------------------------------------------------------------

typedef float  f32x4  __attribute__((ext_vector_type(4)));
typedef short  short8 __attribute__((ext_vector_type(8)));
typedef unsigned long long ull;

#define B_   256
#define T_   1000
#define K_   700
#define H_   64
#define O_   20
#define NKT  22          // ceil(700/32) k-tiles of BK=32
#define TC   10          // v_ro scan chunk length
#define NC   100         // number of v_ro chunks
#define TCL  100         // LIF chunk length
#define NCL  10          // LIF chunks
#define BIL  40          // LIF burn-in steps

// workspace layout (bytes)
#define OFF_WFRAG  ((size_t)0)            // 22*8192 = 180,224
#define OFF_CUR    ((size_t)262144)       // 256000*64*4 = 65,536,000
#define OFF_MASK   ((size_t)65798144)     // 256000*8    =  2,048,000

// ---------------------------------------------------------------------------
// k0: pack W_h into fragment-ordered split-bf16, BK=32 tiles (zero-pad k>=700).
// Per tile kt: hi 4KB (256 chunks) then lo 4KB. Slot s = n*64+lane holds 8
// bf16: h = n*16+(lane&15), k = kt*32 + ((lane>>4)&3)*8 + j.
// ---------------------------------------------------------------------------
__global__ void wprep(const float* __restrict__ Wh, unsigned short* __restrict__ wfrag) {
    int e = blockIdx.x * 256 + threadIdx.x;          // 22*256 = 5632 exact
    int kt   = e >> 8;
    int rem  = e & 255;
    int nf   = rem >> 6;
    int lane = rem & 63;
    int h     = nf * 16 + (lane & 15);
    int kbase = kt * 32 + ((lane >> 4) & 3) * 8;
    unsigned short* dh = wfrag + (size_t)kt * 4096 + (nf * 64 + lane) * 8;
    unsigned short* dl = dh + 2048;
#pragma unroll
    for (int j = 0; j < 8; ++j) {
        int k = kbase + j;
        float v = (k < K_) ? Wh[(size_t)h * K_ + k] : 0.0f;
        unsigned u  = __builtin_bit_cast(unsigned, v);
        float    fh = __builtin_bit_cast(float, u & 0xffff0000u);
        float    r  = v - fh;
        dh[j] = (unsigned short)(u >> 16);
        dl[j] = (unsigned short)(__builtin_bit_cast(unsigned, r) >> 16);
    }
}

// ---------------------------------------------------------------------------
// k1: GEMM  currents[r][h] = sum_k x[r][k]*W_h[h][k] + b_h[h]
// 256 threads (4 waves), 128-row tile, BK=32. Ring of 3 {x 16KB + W 8KB}
// buffers (72KB LDS -> 2 blocks/CU). Stage = 6 glds/wave/tile; counted
// vmcnt(12) keeps 2 tiles in flight across raw s_barriers. Compute is
// pure-LDS. Both x and W LDS layouts XOR-swizzled via pre-swizzled source.
// ---------------------------------------------------------------------------
__device__ __forceinline__ void glds16(const void* src, void* lds) {
    __builtin_amdgcn_global_load_lds(
        (const __attribute__((address_space(1))) void*)src,
        (__attribute__((address_space(3))) void*)lds, 16, 0, 0);
}

__device__ __forceinline__ void splitpair(f32x4 p0, f32x4 p1, short8& hi, short8& lo) {
#pragma unroll
    for (int j = 0; j < 4; ++j) {
        {
            unsigned u  = __builtin_bit_cast(unsigned, p0[j]);
            float    fh = __builtin_bit_cast(float, u & 0xffff0000u);
            float    r  = p0[j] - fh;
            hi[j] = (short)(u >> 16);
            lo[j] = (short)(__builtin_bit_cast(unsigned, r) >> 16);
        }
        {
            unsigned u  = __builtin_bit_cast(unsigned, p1[j]);
            float    fh = __builtin_bit_cast(float, u & 0xffff0000u);
            float    r  = p1[j] - fh;
            hi[j + 4] = (short)(u >> 16);
            lo[j + 4] = (short)(__builtin_bit_cast(unsigned, r) >> 16);
        }
    }
}

// stage one x-tile: 128 rows x 32 k = 16KB = 1024 chunks of 16B.
// LDS phys (row, pcol) holds logical col (pcol ^ (row&7)) -> src pre-swizzled.
__device__ __forceinline__ void stage_x32(const float* __restrict__ x, size_t row0,
                                          int kt, int lane, int wid, float* sbuf) {
#pragma unroll
    for (int j = 0; j < 4; ++j) {
        int c   = j * 256 + wid * 64 + lane;
        int row = c >> 3;
        int col = c & 7;
        int csw = (col ^ (row & 7)) << 4;        // pre-swizzled source byte col
        int kbyte = kt * 128 + csw;
        if (kbyte + 16 > K_ * 4) kbyte = 0;      // tail clamp; value * W_pad(0) = 0
        const char* src = (const char*)(x + (row0 + row) * (size_t)K_) + kbyte;
        float* dst = sbuf + (size_t)(j * 256 + wid * 64) * 4;  // wave-uniform base
        glds16(src, dst);
    }
}

// stage one W-tile: 8KB = 512 chunks; LDS phys chunk c holds logical
// l = c ^ ((c>>4)&7) (involution) -> src pre-swizzled.
__device__ __forceinline__ void stage_w32(const unsigned short* __restrict__ wfrag,
                                          int kt, int lane, int wid, unsigned short* sbuf) {
#pragma unroll
    for (int j = 0; j < 2; ++j) {
        int c = j * 256 + wid * 64 + lane;
        int l = c ^ ((c >> 4) & 7);
        const unsigned short* src = wfrag + (size_t)kt * 4096 + l * 8;
        unsigned short* dst = sbuf + (size_t)(j * 256 + wid * 64) * 8;   // wave-uniform base
        glds16(src, dst);
    }
}

__device__ __forceinline__ void compute32(const float* sbx_, const unsigned short* sbw_,
                                          int lane, int wid, f32x4 (&acc)[2][4]) {
    const f32x4*  xb = (const f32x4*)sbx_;
    const short8* wb = (const short8*)sbw_;
    short8 ah[2], al[2];
    int v0 = (lane >> 4) * 2;
#pragma unroll
    for (int i = 0; i < 2; ++i) {
        int r  = wid * 32 + i * 16 + (lane & 15);
        int c0 = r * 8 + (v0 ^ (r & 7));
        int c1 = r * 8 + ((v0 + 1) ^ (r & 7));
        splitpair(xb[c0], xb[c1], ah[i], al[i]);
    }
#pragma unroll
    for (int n = 0; n < 4; ++n) {
        int lh = n * 64 + lane;
        int ph = lh ^ ((lh >> 4) & 7);
        short8 bhf = wb[ph];
        short8 blf = wb[ph + 256];
#pragma unroll
        for (int i = 0; i < 2; ++i) {
            acc[i][n] = __builtin_amdgcn_mfma_f32_16x16x32_bf16(ah[i], bhf, acc[i][n], 0, 0, 0);
            acc[i][n] = __builtin_amdgcn_mfma_f32_16x16x32_bf16(al[i], bhf, acc[i][n], 0, 0, 0);
            acc[i][n] = __builtin_amdgcn_mfma_f32_16x16x32_bf16(ah[i], blf, acc[i][n], 0, 0, 0);
        }
    }
}

__global__ __launch_bounds__(256, 2) void gemm_cur(const float* __restrict__ x,
                                                   const unsigned short* __restrict__ wfrag,
                                                   const float* __restrict__ b_h,
                                                   float* __restrict__ cur) {
    __shared__ float          sbx[3][4096];   // 3 x 16KB x-tiles
    __shared__ unsigned short sbw[3][4096];   // 3 x  8KB W-tiles
    int tid  = threadIdx.x;
    int lane = tid & 63;
    int wid  = tid >> 6;             // 0..3
    size_t row0 = (size_t)blockIdx.x * 128;

    float bh4[4];
#pragma unroll
    for (int n = 0; n < 4; ++n) bh4[n] = b_h[n * 16 + (lane & 15)];

    f32x4 acc[2][4];
#pragma unroll
    for (int i = 0; i < 2; ++i)
#pragma unroll
        for (int n = 0; n < 4; ++n) acc[i][n] = (f32x4){0.f, 0.f, 0.f, 0.f};

    // prologue: stage tiles 0,1,2 (6 glds each -> 18 outstanding)
    stage_x32(x, row0, 0, lane, wid, sbx[0]);  stage_w32(wfrag, 0, lane, wid, sbw[0]);
    stage_x32(x, row0, 1, lane, wid, sbx[1]);  stage_w32(wfrag, 1, lane, wid, sbw[1]);
    stage_x32(x, row0, 2, lane, wid, sbx[2]);  stage_w32(wfrag, 2, lane, wid, sbw[2]);

#define GSTEP(T, N)                                                          \
    {                                                                        \
        asm volatile("s_waitcnt vmcnt(" #N ")" ::: "memory");                \
        __builtin_amdgcn_s_barrier();                                        \
        compute32(sbx[(T) % 3], sbw[(T) % 3], lane, wid, acc);               \
        asm volatile("s_waitcnt lgkmcnt(0)" ::: "memory");                   \
        __builtin_amdgcn_s_barrier();                                        \
        if ((T) + 3 < NKT) {                                                 \
            stage_x32(x, row0, (T) + 3, lane, wid, sbx[(T) % 3]);            \
            stage_w32(wfrag, (T) + 3, lane, wid, sbw[(T) % 3]);              \
        }                                                                    \
    }
    GSTEP(0, 12)  GSTEP(1, 12)  GSTEP(2, 12)  GSTEP(3, 12)  GSTEP(4, 12)
    GSTEP(5, 12)  GSTEP(6, 12)  GSTEP(7, 12)  GSTEP(8, 12)  GSTEP(9, 12)
    GSTEP(10, 12) GSTEP(11, 12) GSTEP(12, 12) GSTEP(13, 12) GSTEP(14, 12)
    GSTEP(15, 12) GSTEP(16, 12) GSTEP(17, 12) GSTEP(18, 12) GSTEP(19, 12)
    GSTEP(20, 6)  GSTEP(21, 0)
#undef GSTEP

    // epilogue: C/D layout col = lane&15, row = (lane>>4)*4 + j
#pragma unroll
    for (int i = 0; i < 2; ++i) {
        size_t row = row0 + wid * 32 + i * 16 + ((lane >> 4) & 3) * 4;
#pragma unroll
        for (int n = 0; n < 4; ++n) {
#pragma unroll
            for (int j = 0; j < 4; ++j) {
                cur[(row + j) * H_ + n * 16 + (lane & 15)] = acc[i][n][j] + bh4[n];
            }
        }
    }
}

// ---------------------------------------------------------------------------
// k2: LIF, chunked speculative. One wave per (batch, chunk); lane = neuron.
// ---------------------------------------------------------------------------
__global__ __launch_bounds__(64) void lif(const float* __restrict__ cur, ull* __restrict__ masks) {
    int b = blockIdx.x & 255;
    int c = blockIdx.x >> 8;
    int h = threadIdx.x;
    int t0 = c * TCL;
    int ts = (c == 0) ? 0 : (t0 - BIL);
    const float* p = cur + ((size_t)b * T_ + ts) * H_ + h;
    ull* mp = masks + (size_t)b * T_;
    float v = 0.0f;
#pragma unroll 8
    for (int t = ts; t < t0; ++t) {
        float cc = *p; p += H_;
        v = (v + cc) * 0.5f;
        v = (v >= 1.0f) ? 0.0f : v;
    }
#pragma unroll 8
    for (int t = t0; t < t0 + TCL; ++t) {
        float cc = *p; p += H_;
        v = (v + cc) * 0.5f;
        bool s = (v >= 1.0f);
        ull m = __ballot(s);
        if (h == 0) mp[t] = m;
        v = s ? 0.0f : v;
    }
}

// ---------------------------------------------------------------------------
// k3: fused readout, one block per batch (128 threads).
// ---------------------------------------------------------------------------
__global__ __launch_bounds__(128) void readout(const ull* __restrict__ masks,
                                               const float* __restrict__ Wr,
                                               const float* __restrict__ br,
                                               const float* __restrict__ tau,
                                               float* __restrict__ out) {
    __shared__ __align__(16) float wt[64][20];     // wt[h][o]
    __shared__ ull  smask[T_];
    __shared__ __align__(16) float E[NC][20];
    __shared__ __align__(16) float Sv[NC][20];
    __shared__ __align__(16) float pacc[NC][20];
    __shared__ __align__(16) float sScale[20], sBase[20], sBeta[20];

    int tid = threadIdx.x;
    int b   = blockIdx.x;
    for (int i = tid; i < 1280; i += 128) wt[i & 63][i >> 6] = Wr[(size_t)(i >> 6) * 64 + (i & 63)];
    for (int i = tid; i < T_; i += 128) smask[i] = masks[(size_t)b * T_ + i];
    if (tid < 20) {
        float beta = 1.0f / (1.0f + __expf(-tau[tid]));
        sBeta[tid]  = beta;
        sScale[tid] = 1.0f - beta;
        sBase[tid]  = br[tid];
    }
    __syncthreads();

    // phase 1: scanE — items (c, o4), 500 total
    for (int it = tid; it < NC * 5; it += 128) {
        int o4 = it % 5;
        int c  = it / 5;
        f32x4 beta4  = *(const f32x4*)&sBeta[o4 * 4];
        f32x4 scale4 = *(const f32x4*)&sScale[o4 * 4];
        f32x4 base4  = *(const f32x4*)&sBase[o4 * 4];
        f32x4 v = {0.f, 0.f, 0.f, 0.f};
        const ull* mp = smask + c * TC;
        for (int j = 0; j < TC; ++j) {
            ull m = mp[j];
            f32x4 a = {0.f, 0.f, 0.f, 0.f};
            while (m) {
                int h = __builtin_ctzll(m);
                m &= (m - 1);
                a += *(const f32x4*)&wt[h][o4 * 4];
            }
            f32x4 q;
#pragma unroll
            for (int jj = 0; jj < 4; ++jj) q[jj] = scale4[jj] * (base4[jj] + a[jj]);
            v = beta4 * v + q;
        }
        *(f32x4*)&E[c][o4 * 4] = v;
    }
    __syncthreads();

    // phase 2: carry
    if (tid < 20) {
        int o = tid;
        float beta = sBeta[o];
        float bp = 1.0f;
#pragma unroll
        for (int i = 0; i < TC; ++i) bp *= beta;
        float s = 0.0f;
        for (int c = 0; c < NC; ++c) {
            Sv[c][o] = s;
            s = bp * s + E[c][o];
        }
    }
    __syncthreads();

    // phase 3: scanSoft — thread c < 100
    if (tid < NC) {
        int c = tid;
        float beta[20], v[20], acc[20];
#pragma unroll
        for (int o = 0; o < 20; ++o) {
            beta[o] = sBeta[o];
            v[o]   = Sv[c][o];
            acc[o] = 0.0f;
        }
        int t0 = c * TC;
        const ull* mp = smask + t0;
        for (int j = 0; j < TC; ++j) {
            int t = t0 + j;
            ull m = mp[j];
            f32x4 a[5];
#pragma unroll
            for (int i = 0; i < 5; ++i) a[i] = (f32x4){0.f, 0.f, 0.f, 0.f};
            while (m) {
                int h = __builtin_ctzll(m);
                m &= (m - 1);
                const f32x4* w4 = (const f32x4*)&wt[h][0];
#pragma unroll
                for (int i = 0; i < 5; ++i) a[i] += w4[i];
            }
#pragma unroll
            for (int o = 0; o < 20; ++o) {
                float q = sScale[o] * (sBase[o] + a[o >> 2][o & 3]);
                v[o] = beta[o] * v[o] + q;
            }
            if (t >= 11) {
                float mx = v[0];
#pragma unroll
                for (int o = 1; o < 20; ++o) mx = fmaxf(mx, v[o]);
                float e[20], ssum = 0.0f;
#pragma unroll
                for (int o = 0; o < 20; ++o) { e[o] = __expf(v[o] - mx); ssum += e[o]; }
                float inv = 1.0f / ssum;
#pragma unroll
                for (int o = 0; o < 20; ++o) acc[o] += e[o] * inv;
            }
        }
#pragma unroll
        for (int o = 0; o < 20; ++o) pacc[c][o] = acc[o];
    }
    __syncthreads();

    // phase 4: reduce
    if (tid < 20) {
        float s = 0.0f;
        for (int c = 0; c < NC; ++c) s += pacc[c][tid];
        out[(size_t)b * 20 + tid] = s;
    }
}

// ---------------------------------------------------------------------------
extern "C" void kernel_launch(void* const* d_in, const int* in_sizes, int n_in,
                              void* d_out, int out_size, void* d_ws, size_t ws_size,
                              hipStream_t stream) {
    const float* x   = (const float*)d_in[0];
    const float* W_h = (const float*)d_in[1];
    const float* b_h = (const float*)d_in[2];
    const float* W_r = (const float*)d_in[3];
    const float* b_r = (const float*)d_in[4];
    const float* tau = (const float*)d_in[5];

    char* ws = (char*)d_ws;
    unsigned short* wfrag = (unsigned short*)(ws + OFF_WFRAG);
    float* cur  = (float*)(ws + OFF_CUR);
    ull*   msk  = (ull*)(ws + OFF_MASK);
    float* out  = (float*)d_out;

    wprep<<<22, 256, 0, stream>>>(W_h, wfrag);
    gemm_cur<<<2000, 256, 0, stream>>>(x, wfrag, b_h, cur);
    lif<<<NCL * 256, 64, 0, stream>>>(cur, msk);
    readout<<<256, 128, 0, stream>>>(msk, W_r, b_r, tau, out);
}